// Round 1
// 553.546 us; speedup vs baseline: 1.0786x; 1.0786x over previous
//
#include <hip/hip_runtime.h>

// PulseFloatingPointEncoder: per element emit 8 fp32 flags
// [sign, e3, e2, e1, e0, m2, m1, m0] of a truncated e4m3-style encoding.
// E_BITS=4, M_BITS=3, N_INT=10, N_DEC=10, BIAS=7, START_EXP=17, SUB_START=16.
//
// V2: vectorized float4 loads (16 B/lane), LDS-staged XOR-swizzled output so
// global stores are fully coalesced 16 B/lane contiguous (full 128-B lines),
// nontemporal hints on the 512 MiB streaming output.

typedef float f32x4 __attribute__((ext_vector_type(4)));

__device__ __forceinline__ void encode_one(float x, f32x4& lo, f32x4& hi) {
    float sign = (x < 0.0f) ? 1.0f : 0.0f;   // note: -0.0f -> 0 (matches ref x<0)
    unsigned ub = __float_as_uint(x) & 0x7fffffffu;
    float a = __uint_as_float(ub);
    int e_lead = (int)(ub >> 23) - 127;      // floor(log2 a) for normals; <=-127 for subnorm/zero

    int ec, mant;
    if (__builtin_expect(e_lead >= 10, 0)) {
        // a >= 1024 (or inf/nan): faithful emulation of the reference greedy scan.
        float V = a;
        int has_fired = 0, d0 = 0, d1 = 0, d2 = 0;
        int e_reg = 0, m0 = 0, m1 = 0, m2 = 0;
        for (int t = 0; t < 20; ++t) {
            float thr = __builtin_exp2f((float)(9 - t));   // exact powers of two
            int s = (V >= thr) ? 1 : 0;
            if (s) V -= thr;                                // exact: V - s*thr
            int fs = s & (has_fired ^ 1);
            int active = (t < 16) ? 1 : 0;
            int counter = (16 - t) > 0 ? (16 - t) : 0;
            if (fs & active) e_reg |= (counter & 15);
            if (s) { m0 |= d0; m1 |= d1; m2 |= d2; }
            int vfs = fs & active;
            d2 = d1; d1 = d0; d0 = vfs;
            has_fired |= vfs;
            if (t >= 16 && t <= 18) {
                int bit = s & (has_fired ^ 1);
                if (t == 16) m0 |= bit; else if (t == 17) m1 |= bit; else m2 |= bit;
            }
        }
        ec = e_reg;
        mant = (m0 << 2) | (m1 << 1) | m2;
    } else {
        bool norm = (e_lead >= -6);
        bool sub  = (e_lead >= -10) & !norm;
        // normal: exponent code (7+e_lead)&15, mantissa = top 3 fraction bits (truncate)
        int ec_n   = (7 + e_lead) & 15;
        int mant_n = (int)(ub >> 20) & 7;
        // subnormal range [2^-10, 2^-6): bits at weights 2^-7..2^-9
        int mant_s = ((int)(a * 512.0f)) & 7;   // a*512 in [0.5, 8), exact scaling, trunc
        ec   = norm ? ec_n : 0;
        mant = norm ? mant_n : (sub ? mant_s : 0);
    }

    lo.x = sign;
    lo.y = (float)((ec >> 3) & 1);   // e_out is e_reg reversed => MSB first
    lo.z = (float)((ec >> 2) & 1);
    lo.w = (float)((ec >> 1) & 1);
    hi.x = (float)(ec & 1);
    hi.y = (float)((mant >> 2) & 1); // m_reg[0] = most significant mantissa bit
    hi.z = (float)((mant >> 1) & 1);
    hi.w = (float)(mant & 1);
}

// Main kernel: 256 threads/block, 4 elements/thread -> 1024 elements/block.
// Output per block: 2048 f32x4 slots (32 KiB), staged in LDS so the global
// stores are lane-contiguous dwordx4 (1 KiB per wave instruction).
//
// LDS swizzle: slot s stored at s ^ ((s>>3)&7). Writer (thread t, slots
// 8t..8t+7): xor key = t&7 -> per ds_write_b128 instruction, 16 consecutive
// lanes cover each 4-bank group exactly 2x (conflict-free). Reader (slot
// t+256k): xor key = (t>>3)&7, same 2-lanes/bank-group property.
__global__ __launch_bounds__(256) void pulse_encode_kernel(
        const f32x4* __restrict__ in4, f32x4* __restrict__ out4) {
    __shared__ f32x4 lds[2048];
    const int t = threadIdx.x;
    const int blk = blockIdx.x;

    f32x4 v = __builtin_nontemporal_load(&in4[blk * 256 + t]);

    f32x4 lo0, hi0, lo1, hi1, lo2, hi2, lo3, hi3;
    encode_one(v.x, lo0, hi0);
    encode_one(v.y, lo1, hi1);
    encode_one(v.z, lo2, hi2);
    encode_one(v.w, lo3, hi3);

    const int base = t * 8;
    const int sw = t & 7;        // == ((base+j)>>3)&7 for j in [0,8)
    lds[(base + 0) ^ sw] = lo0;
    lds[(base + 1) ^ sw] = hi0;
    lds[(base + 2) ^ sw] = lo1;
    lds[(base + 3) ^ sw] = hi1;
    lds[(base + 4) ^ sw] = lo2;
    lds[(base + 5) ^ sw] = hi2;
    lds[(base + 6) ^ sw] = lo3;
    lds[(base + 7) ^ sw] = hi3;

    __syncthreads();

    const int obase = blk * 2048;
    const int rsw = (t >> 3) & 7;
#pragma unroll
    for (int k = 0; k < 8; ++k) {
        int s = t + 256 * k;
        f32x4 val = lds[s ^ rsw];
        __builtin_nontemporal_store(val, &out4[obase + s]);
    }
}

// Tail kernel (n not a multiple of 1024): original scalar path.
__global__ __launch_bounds__(256) void pulse_encode_tail(
        const float* __restrict__ in, f32x4* __restrict__ out, int n) {
    int i = blockIdx.x * 256 + threadIdx.x;
    if (i >= n) return;
    f32x4 lo, hi;
    encode_one(in[i], lo, hi);
    out[2 * i]     = lo;
    out[2 * i + 1] = hi;
}

extern "C" void kernel_launch(void* const* d_in, const int* in_sizes, int n_in,
                              void* d_out, int out_size, void* d_ws, size_t ws_size,
                              hipStream_t stream) {
    const float* x = (const float*)d_in[0];
    f32x4* out = (f32x4*)d_out;
    int n = in_sizes[0];                  // 8*2048*1024 = 16,777,216
    int nblocks = n / 1024;               // full 1024-element blocks
    if (nblocks > 0) {
        pulse_encode_kernel<<<nblocks, 256, 0, stream>>>(
            (const f32x4*)x, out);
    }
    int done = nblocks * 1024;
    int rem = n - done;
    if (rem > 0) {
        int tb = (rem + 255) / 256;
        pulse_encode_tail<<<tb, 256, 0, stream>>>(x + done, out + 2 * done, rem);
    }
}